// Round 1
// baseline (380.808 us; speedup 1.0000x reference)
//
#include <hip/hip_runtime.h>
#include <math.h>

#define CHN 128
#define TT 16384
#define NBATCH 8
#define KCONST 196608      // 128*128*3*4
#define TILE_T 64
#define GUARD 8
#define CRANGE 96          // computed range per layer: [T0-16, T0+80)
#define ROWS 112           // CRANGE + 2*GUARD, t = T0 - 24 + row
#define LROW 136           // padded LDS row stride in ushorts (16B-aligned rows)

typedef __bf16 bf16x8 __attribute__((ext_vector_type(8)));
typedef float  f32x4  __attribute__((ext_vector_type(4)));
typedef unsigned short u16x8 __attribute__((ext_vector_type(8)));
typedef unsigned short u16x4 __attribute__((ext_vector_type(4)));

__device__ __forceinline__ unsigned short f2bf(float f) {
    union { float f; unsigned int u; } v; v.f = f;
    unsigned int u = v.u;
    u += 0x7fffu + ((u >> 16) & 1u);   // round-to-nearest-even
    return (unsigned short)(u >> 16);
}
__device__ __forceinline__ float b2f(unsigned short h) {
    union { float f; unsigned int u; } v; v.u = ((unsigned int)h) << 16;
    return v.f;
}

__device__ __forceinline__ float gelu_exact(float x) {
    return 0.5f * x * (1.0f + erff(x * 0.70710678118654752f));
}

// ------------- Kernel 1a: conv0 (80->64, k=5, pad=2) + gelu -> h0 -------------
__global__ __launch_bounds__(256) void k_cond0(
    const float* __restrict__ cond, const float* __restrict__ w0,
    const float* __restrict__ b0, float* __restrict__ h0)
{
    __shared__ float cS[80 * 32];
    __shared__ float wS[8 * 80 * 5];
    __shared__ float bS[8];
    int b = blockIdx.x >> 3, g = blockIdx.x & 7;
    int tid = threadIdx.x;

    for (int idx = tid; idx < 80 * 32; idx += 256) cS[idx] = cond[b * 2560 + idx];
    for (int idx = tid; idx < 8 * 400; idx += 256) wS[idx] = w0[g * 3200 + idx];
    if (tid < 8) bS[tid] = b0[g * 8 + tid];
    __syncthreads();

    int oc = tid >> 5, t = tid & 31;
    float acc = bS[oc];
    const float* wr = wS + oc * 400;
    for (int ic = 0; ic < 80; ++ic) {
        const float* cr = cS + ic * 32;
        #pragma unroll
        for (int j = 0; j < 5; ++j) {
            int tv = t - 2 + j;
            if (tv >= 0 && tv < 32) acc += wr[ic * 5 + j] * cr[tv];
        }
    }
    h0[(b * 64 + g * 8 + oc) * 32 + t] = gelu_exact(acc);
}

// ------ Kernel 1b: conv1 (64->64, k=3, pad=1) + gelu + mean_t -> hbar --------
__global__ __launch_bounds__(256) void k_cond1(
    const float* __restrict__ h0, const float* __restrict__ w1,
    const float* __restrict__ b1, float* __restrict__ hbar)
{
    __shared__ float hS[64 * 32];
    __shared__ float wS[8 * 64 * 3];
    __shared__ float bS[8];
    int b = blockIdx.x >> 3, g = blockIdx.x & 7;
    int tid = threadIdx.x;

    for (int idx = tid; idx < 64 * 32; idx += 256) hS[idx] = h0[b * 2048 + idx];
    for (int idx = tid; idx < 8 * 192; idx += 256) wS[idx] = w1[g * 1536 + idx];
    if (tid < 8) bS[tid] = b1[g * 8 + tid];
    __syncthreads();

    int oc = tid >> 5, t = tid & 31;
    float acc = bS[oc];
    const float* wr = wS + oc * 192;
    for (int ic = 0; ic < 64; ++ic) {
        const float* hr = hS + ic * 32;
        #pragma unroll
        for (int j = 0; j < 3; ++j) {
            int tv = t - 1 + j;
            if (tv >= 0 && tv < 32) acc += wr[ic * 3 + j] * hr[tv];
        }
    }
    float v = gelu_exact(acc);
    #pragma unroll
    for (int off = 1; off < 32; off <<= 1) v += __shfl_xor(v, off, 64);
    if (t == 0) hbar[b * 64 + g * 8 + oc] = v * (1.0f / 32.0f);
}

// ---- Kernel 2: kernels/biases. LDS-staged coalesced w2 reads. ----
__global__ __launch_bounds__(256) void k_weights(
    const float* __restrict__ w2, const float* __restrict__ b2,
    const float* __restrict__ hbar,
    unsigned short* __restrict__ W, float* __restrict__ bmean)
{
    __shared__ float hS[8 * 64];
    __shared__ float buf[256 * 68];   // 256 rows x 64 floats, +4 pad
    int tid = threadIdx.x;
    for (int idx = tid; idx < 512; idx += 256) hS[idx] = hbar[idx];

    // stage this block's 256 w2 rows (64 KB) via coalesced float4 stream
    const float4* src4 = (const float4*)(w2 + (long)blockIdx.x * 16384);
    #pragma unroll
    for (int it = 0; it < 16; ++it) {
        int f = it * 256 + tid;
        float4 v = src4[f];
        int row = f >> 4, col = f & 15;
        *(float4*)&buf[row * 68 + col * 4] = v;
    }
    __syncthreads();

    long p = (long)blockIdx.x * 256 + tid;   // [0, 197632), exact
    const float* rowp = &buf[tid * 68];
    float acc[8];
    #pragma unroll
    for (int bb = 0; bb < 8; ++bb) acc[bb] = 0.f;
    #pragma unroll
    for (int q = 0; q < 16; ++q) {
        float4 wv = *(const float4*)&rowp[q * 4];
        #pragma unroll
        for (int bb = 0; bb < 8; ++bb) {
            const float* h = hS + bb * 64 + q * 4;
            acc[bb] += wv.x * h[0] + wv.y * h[1] + wv.z * h[2] + wv.w * h[3];
        }
    }
    float bias = b2[p];
    if (p < KCONST) {
        int i = (int)(p / 49152); int r = (int)(p % 49152);
        int o = r / 384; int m = r % 384; int c = m / 3; int tp = m % 3;
        #pragma unroll
        for (int bb = 0; bb < 8; ++bb)
            W[(long)((bb * 4 + i) * 128 + o) * 384 + tp * 128 + c] =
                f2bf(acc[bb] + bias);
    } else {
        int q = (int)(p - KCONST); int i = q >> 7, o = q & 127;
        #pragma unroll
        for (int bb = 0; bb < 8; ++bb)
            bmean[(bb * 4 + i) * 128 + o] = acc[bb] + bias;
    }
}

// ------ Kernel 3: ALL 4 dilated conv layers fused, signal lives in LDS ------
// v2: the fp32 residual chain lives in the MFMA accumulator (C-in carries x_l
// across layers; acc is never re-zeroed). LDS holds ONLY the bf16 hi image
// (30,464 B) for the MFMA B-operand; no xlo buffer, no LDS residual reads.
// Layer-0 residual is a guarded fp32 re-read of x (L2-hot: same tile the
// block just staged). A-fragments load per-ks inside the K-loop to keep
// registers under the 128 cap -> 4 blocks/CU (was 2).
// All layers compute the same aligned 96-row range [T0-16,T0+80) (rows
// 8..104); stale guard rows only corrupt edge outputs that validity analysis
// discards: valid y3 superset [T0-2, T0+66) superset of the stored [T0, T0+64).
__global__ __launch_bounds__(256, 4) void k_fused(
    const float* __restrict__ src, float* __restrict__ dst,
    const unsigned short* __restrict__ W, const float* __restrict__ bmean,
    const float* __restrict__ alpha)
{
    __shared__ __align__(16) unsigned short xhi[ROWS * LROW];  // 30464 B

    int tid  = threadIdx.x;
    int lane = tid & 63;
    int wave = tid >> 6;
    int b    = blockIdx.x >> 8;
    int tile = blockIdx.x & 255;
    int T0   = tile * TILE_T;

    int nrow = lane & 15;
    int quad = lane >> 4;
    int o0   = wave * 32;

    const float* xb = src + (long)b * CHN * TT;

    // --- stage x (hi only): each wave covers its 32-c slice over all 112
    //     rows; lane->t (coalesced global), 8-wide c chunks -> b128 LDS writes
    {
        int cb = wave * 32;
        #pragma unroll 1
        for (int pass = 0; pass < 2; ++pass) {
            int tl = pass * 64 + lane;
            if (tl < ROWS) {
                int tg = T0 - 24 + tl;
                bool ok = (tg >= 0) && (tg < TT);
                #pragma unroll
                for (int kb = 0; kb < 4; ++kb) {
                    float v[8];
                    #pragma unroll
                    for (int k = 0; k < 8; ++k)
                        v[k] = ok ? xb[(long)(cb + kb * 8 + k) * TT + tg] : 0.f;
                    u16x8 h;
                    #pragma unroll
                    for (int k = 0; k < 8; ++k) h[k] = f2bf(v[k]);
                    *(u16x8*)&xhi[tl * LROW + cb + kb * 8] = h;
                }
            }
        }
    }

    // persistent fp32 accumulator = the residual chain (x_l), never re-zeroed
    f32x4 acc[2][6];
    #pragma unroll
    for (int mt = 0; mt < 2; ++mt)
        #pragma unroll
        for (int nt = 0; nt < 6; ++nt)
            acc[mt][nt] = (f32x4){0.f, 0.f, 0.f, 0.f};

    __syncthreads();

    #pragma unroll 1
    for (int l = 0; l < 4; ++l) {
        const int d = 1 << l;
        const unsigned short* Wl = W + (long)((b * 4 + l) * 128) * 384;
        const float* bm = bmean + (b * 4 + l) * 128;

        // K-loop over kk = tap*128 + c; A-frags loaded per-ks (low VGPR),
        // B-frag read once feeds both m-tiles; MFMA C-in carries x_l (fp32)
        #pragma unroll
        for (int ks = 0; ks < 12; ++ks) {
            const int c0 = (ks & 3) * 32 + quad * 8;
            const int roff = GUARD + nrow + ((ks >> 2) - 1) * d;
            const unsigned short* wr =
                Wl + (long)(o0 + nrow) * 384 + ks * 32 + quad * 8;
            bf16x8 a0 = *(const bf16x8*)(wr);
            bf16x8 a1 = *(const bf16x8*)(wr + 16 * 384);
            #pragma unroll
            for (int nt = 0; nt < 6; ++nt) {
                bf16x8 bf = *(const bf16x8*)&xhi[(roff + nt * 16) * LROW + c0];
                acc[0][nt] = __builtin_amdgcn_mfma_f32_16x16x32_bf16(
                    a0, bf, acc[0][nt], 0, 0, 0);
                acc[1][nt] = __builtin_amdgcn_mfma_f32_16x16x32_bf16(
                    a1, bf, acc[1][nt], 0, 0, 0);
            }
        }

        // fold bias (+ layer-0 fp32 residual from global, L2-hot) into acc
        if (l == 0) {
            #pragma unroll
            for (int mt = 0; mt < 2; ++mt) {
                int obase = o0 + mt * 16 + quad * 4;
                float bias[4];
                #pragma unroll
                for (int r = 0; r < 4; ++r) bias[r] = bm[obase + r];
                #pragma unroll
                for (int nt = 0; nt < 6; ++nt) {
                    int tg = T0 - 16 + nt * 16 + nrow;
                    bool ok = ((unsigned)tg < (unsigned)TT);
                    #pragma unroll
                    for (int r = 0; r < 4; ++r) {
                        float xf = ok ? xb[(long)(obase + r) * TT + tg] : 0.f;
                        acc[mt][nt][r] += xf + bias[r];
                    }
                }
            }
        } else {
            #pragma unroll
            for (int mt = 0; mt < 2; ++mt) {
                int obase = o0 + mt * 16 + quad * 4;
                float bias[4];
                #pragma unroll
                for (int r = 0; r < 4; ++r) bias[r] = bm[obase + r];
                #pragma unroll
                for (int nt = 0; nt < 6; ++nt) {
                    #pragma unroll
                    for (int r = 0; r < 4; ++r)
                        acc[mt][nt][r] += bias[r];
                }
            }
        }
        __syncthreads();   // all LDS reads of layer l done before any write

        if (l < 3) {
            // write back only the bf16 hi image for the next layer's B-operand
            #pragma unroll
            for (int mt = 0; mt < 2; ++mt) {
                int obase = o0 + mt * 16 + quad * 4;
                #pragma unroll
                for (int nt = 0; nt < 6; ++nt) {
                    int trow = GUARD + nt * 16 + nrow;
                    int tg = T0 - 16 + nt * 16 + nrow;
                    bool ok = ((unsigned)tg < (unsigned)TT);
                    u16x4 h;
                    #pragma unroll
                    for (int r = 0; r < 4; ++r) {
                        float v = ok ? acc[mt][nt][r] : 0.f;
                        h[r] = f2bf(v);
                    }
                    *(u16x4*)&xhi[trow * LROW + obase] = h;
                }
            }
            __syncthreads();
        } else {
            // final layer: sin activation, store only the valid 64-t core
            #pragma unroll
            for (int mt = 0; mt < 2; ++mt) {
                #pragma unroll
                for (int r = 0; r < 4; ++r) {
                    int o = o0 + mt * 16 + quad * 4 + r;
                    float av = alpha[o];
                    float rcp = 1.0f / (av + 1e-8f);
                    long rowoff = ((long)b * CHN + o) * TT + T0;
                    #pragma unroll
                    for (int nt = 1; nt < 5; ++nt) {
                        int t = (nt - 1) * 16 + nrow;
                        float xn = acc[mt][nt][r];
                        float s = __sinf(av * xn);
                        dst[rowoff + t] = xn + rcp * s * s;
                    }
                }
            }
        }
    }
}

extern "C" void kernel_launch(void* const* d_in, const int* in_sizes, int n_in,
                              void* d_out, int out_size, void* d_ws, size_t ws_size,
                              hipStream_t stream) {
    const float* x     = (const float*)d_in[0];
    const float* cond  = (const float*)d_in[1];
    const float* w0    = (const float*)d_in[2];
    const float* b0    = (const float*)d_in[3];
    const float* w1    = (const float*)d_in[4];
    const float* b1    = (const float*)d_in[5];
    const float* w2    = (const float*)d_in[6];
    const float* b2    = (const float*)d_in[7];
    const float* alpha = (const float*)d_in[8];
    float* out = (float*)d_out;

    char* ws = (char*)d_ws;
    unsigned short* W = (unsigned short*)ws;               // 3,145,728 B
    float* bmean = (float*)(ws + 3145728);                 // 16,384 B
    float* hbar  = (float*)(ws + 3162112);                 // 2,048 B
    float* h0    = (float*)(ws + 3164160);                 // 65,536 B

    k_cond0<<<64, 256, 0, stream>>>(cond, w0, b0, h0);
    k_cond1<<<64, 256, 0, stream>>>(h0, w1, b1, hbar);
    k_weights<<<772, 256, 0, stream>>>(w2, b2, hbar, W, bmean);
    k_fused<<<2048, 256, 0, stream>>>(x, out, W, bmean, alpha);
}

// Round 2
// 332.478 us; speedup vs baseline: 1.1454x; 1.1454x over previous
//
#include <hip/hip_runtime.h>
#include <math.h>

#define CHN 128
#define TT 16384
#define NBATCH 8
#define KCONST 196608      // 128*128*3*4
#define TILE_T 64
#define GUARD 8
#define CRANGE 96          // computed range per layer: [T0-16, T0+80)
#define ROWS 112           // CRANGE + 2*GUARD, t = T0 - 24 + row
#define LROW 136           // padded LDS row stride in ushorts (16B-aligned rows)

typedef __bf16 bf16x8 __attribute__((ext_vector_type(8)));
typedef float  f32x4  __attribute__((ext_vector_type(4)));
typedef unsigned short u16x8 __attribute__((ext_vector_type(8)));
typedef unsigned short u16x4 __attribute__((ext_vector_type(4)));

__device__ __forceinline__ unsigned short f2bf(float f) {
    union { float f; unsigned int u; } v; v.f = f;
    unsigned int u = v.u;
    u += 0x7fffu + ((u >> 16) & 1u);   // round-to-nearest-even
    return (unsigned short)(u >> 16);
}
__device__ __forceinline__ float b2f(unsigned short h) {
    union { float f; unsigned int u; } v; v.u = ((unsigned int)h) << 16;
    return v.f;
}

__device__ __forceinline__ float gelu_exact(float x) {
    return 0.5f * x * (1.0f + erff(x * 0.70710678118654752f));
}

// ------------- Kernel 1a: conv0 (80->64, k=5, pad=2) + gelu -> h0 -------------
__global__ __launch_bounds__(256) void k_cond0(
    const float* __restrict__ cond, const float* __restrict__ w0,
    const float* __restrict__ b0, float* __restrict__ h0)
{
    __shared__ float cS[80 * 32];
    __shared__ float wS[8 * 80 * 5];
    __shared__ float bS[8];
    int b = blockIdx.x >> 3, g = blockIdx.x & 7;
    int tid = threadIdx.x;

    for (int idx = tid; idx < 80 * 32; idx += 256) cS[idx] = cond[b * 2560 + idx];
    for (int idx = tid; idx < 8 * 400; idx += 256) wS[idx] = w0[g * 3200 + idx];
    if (tid < 8) bS[tid] = b0[g * 8 + tid];
    __syncthreads();

    int oc = tid >> 5, t = tid & 31;
    float acc = bS[oc];
    const float* wr = wS + oc * 400;
    for (int ic = 0; ic < 80; ++ic) {
        const float* cr = cS + ic * 32;
        #pragma unroll
        for (int j = 0; j < 5; ++j) {
            int tv = t - 2 + j;
            if (tv >= 0 && tv < 32) acc += wr[ic * 5 + j] * cr[tv];
        }
    }
    h0[(b * 64 + g * 8 + oc) * 32 + t] = gelu_exact(acc);
}

// ------ Kernel 1b: conv1 (64->64, k=3, pad=1) + gelu + mean_t -> hbar --------
__global__ __launch_bounds__(256) void k_cond1(
    const float* __restrict__ h0, const float* __restrict__ w1,
    const float* __restrict__ b1, float* __restrict__ hbar)
{
    __shared__ float hS[64 * 32];
    __shared__ float wS[8 * 64 * 3];
    __shared__ float bS[8];
    int b = blockIdx.x >> 3, g = blockIdx.x & 7;
    int tid = threadIdx.x;

    for (int idx = tid; idx < 64 * 32; idx += 256) hS[idx] = h0[b * 2048 + idx];
    for (int idx = tid; idx < 8 * 192; idx += 256) wS[idx] = w1[g * 1536 + idx];
    if (tid < 8) bS[tid] = b1[g * 8 + tid];
    __syncthreads();

    int oc = tid >> 5, t = tid & 31;
    float acc = bS[oc];
    const float* wr = wS + oc * 192;
    for (int ic = 0; ic < 64; ++ic) {
        const float* hr = hS + ic * 32;
        #pragma unroll
        for (int j = 0; j < 3; ++j) {
            int tv = t - 1 + j;
            if (tv >= 0 && tv < 32) acc += wr[ic * 3 + j] * hr[tv];
        }
    }
    float v = gelu_exact(acc);
    #pragma unroll
    for (int off = 1; off < 32; off <<= 1) v += __shfl_xor(v, off, 64);
    if (t == 0) hbar[b * 64 + g * 8 + oc] = v * (1.0f / 32.0f);
}

// ---- Kernel 2: kernels/biases. LDS-staged coalesced w2 reads. ----
__global__ __launch_bounds__(256) void k_weights(
    const float* __restrict__ w2, const float* __restrict__ b2,
    const float* __restrict__ hbar,
    unsigned short* __restrict__ W, float* __restrict__ bmean)
{
    __shared__ float hS[8 * 64];
    __shared__ float buf[256 * 68];   // 256 rows x 64 floats, +4 pad
    int tid = threadIdx.x;
    for (int idx = tid; idx < 512; idx += 256) hS[idx] = hbar[idx];

    // stage this block's 256 w2 rows (64 KB) via coalesced float4 stream
    const float4* src4 = (const float4*)(w2 + (long)blockIdx.x * 16384);
    #pragma unroll
    for (int it = 0; it < 16; ++it) {
        int f = it * 256 + tid;
        float4 v = src4[f];
        int row = f >> 4, col = f & 15;
        *(float4*)&buf[row * 68 + col * 4] = v;
    }
    __syncthreads();

    long p = (long)blockIdx.x * 256 + tid;   // [0, 197632), exact
    const float* rowp = &buf[tid * 68];
    float acc[8];
    #pragma unroll
    for (int bb = 0; bb < 8; ++bb) acc[bb] = 0.f;
    #pragma unroll
    for (int q = 0; q < 16; ++q) {
        float4 wv = *(const float4*)&rowp[q * 4];
        #pragma unroll
        for (int bb = 0; bb < 8; ++bb) {
            const float* h = hS + bb * 64 + q * 4;
            acc[bb] += wv.x * h[0] + wv.y * h[1] + wv.z * h[2] + wv.w * h[3];
        }
    }
    float bias = b2[p];
    if (p < KCONST) {
        int i = (int)(p / 49152); int r = (int)(p % 49152);
        int o = r / 384; int m = r % 384; int c = m / 3; int tp = m % 3;
        #pragma unroll
        for (int bb = 0; bb < 8; ++bb)
            W[(long)((bb * 4 + i) * 128 + o) * 384 + tp * 128 + c] =
                f2bf(acc[bb] + bias);
    } else {
        int q = (int)(p - KCONST); int i = q >> 7, o = q & 127;
        #pragma unroll
        for (int bb = 0; bb < 8; ++bb)
            bmean[(bb * 4 + i) * 128 + o] = acc[bb] + bias;
    }
}

// ------ Kernel 3: ALL 4 dilated conv layers fused, signal lives in LDS ------
// v3: fp32 residual chain lives in the MFMA accumulator (C-in carries x_l
// across layers; acc never re-zeroed). acc is INITIALIZED from x (fp32 global
// read) before the first barrier, while this wave's staging pass has the same
// 32-channel slice L1/L2-hot (cb == o0) -- no cold post-K-loop re-read.
// LDS holds only the bf16 hi image (30,464 B). __launch_bounds__(256,3):
// round-1's (256,4) 128-reg cap made the allocator spill ~400 MB of scratch
// (WRITE_SIZE 68->278 MB); cap 170 fits acc(48 AGPR)+K-loop working set.
// All layers compute the same aligned 96-row range [T0-16,T0+80) (rows
// 8..104); stale guard rows only corrupt edge outputs that validity analysis
// discards: valid y3 superset [T0-2, T0+66) superset of the stored [T0, T0+64).
__global__ __launch_bounds__(256, 3) void k_fused(
    const float* __restrict__ src, float* __restrict__ dst,
    const unsigned short* __restrict__ W, const float* __restrict__ bmean,
    const float* __restrict__ alpha)
{
    __shared__ __align__(16) unsigned short xhi[ROWS * LROW];  // 30464 B

    int tid  = threadIdx.x;
    int lane = tid & 63;
    int wave = tid >> 6;
    int b    = blockIdx.x >> 8;
    int tile = blockIdx.x & 255;
    int T0   = tile * TILE_T;

    int nrow = lane & 15;
    int quad = lane >> 4;
    int o0   = wave * 32;

    const float* xb = src + (long)b * CHN * TT;

    // --- stage x (hi only): each wave covers its 32-c slice over all 112
    //     rows; lane->t (coalesced global), 8-wide c chunks -> b128 LDS writes
    {
        int cb = wave * 32;
        #pragma unroll 1
        for (int pass = 0; pass < 2; ++pass) {
            int tl = pass * 64 + lane;
            if (tl < ROWS) {
                int tg = T0 - 24 + tl;
                bool ok = (tg >= 0) && (tg < TT);
                #pragma unroll
                for (int kb = 0; kb < 4; ++kb) {
                    float v[8];
                    #pragma unroll
                    for (int k = 0; k < 8; ++k)
                        v[k] = ok ? xb[(long)(cb + kb * 8 + k) * TT + tg] : 0.f;
                    u16x8 h;
                    #pragma unroll
                    for (int k = 0; k < 8; ++k) h[k] = f2bf(v[k]);
                    *(u16x8*)&xhi[tl * LROW + cb + kb * 8] = h;
                }
            }
        }
    }

    // persistent fp32 accumulator = the residual chain: init acc = x (layer-0
    // residual), read now while the staged lines are cache-hot
    f32x4 acc[2][6];
    #pragma unroll
    for (int mt = 0; mt < 2; ++mt) {
        int obase = o0 + mt * 16 + quad * 4;
        #pragma unroll
        for (int nt = 0; nt < 6; ++nt) {
            int tg = T0 - 16 + nt * 16 + nrow;
            bool ok = ((unsigned)tg < (unsigned)TT);
            #pragma unroll
            for (int r = 0; r < 4; ++r)
                acc[mt][nt][r] = ok ? xb[(long)(obase + r) * TT + tg] : 0.f;
        }
    }

    __syncthreads();

    #pragma unroll 1
    for (int l = 0; l < 4; ++l) {
        const int d = 1 << l;
        const unsigned short* Wl = W + (long)((b * 4 + l) * 128) * 384;
        const float* bm = bmean + (b * 4 + l) * 128;

        // K-loop over kk = tap*128 + c; A-frags loaded per-ks (low VGPR),
        // B-frag read once feeds both m-tiles; MFMA C-in carries x_l (fp32)
        #pragma unroll
        for (int ks = 0; ks < 12; ++ks) {
            const int c0 = (ks & 3) * 32 + quad * 8;
            const int roff = GUARD + nrow + ((ks >> 2) - 1) * d;
            const unsigned short* wr =
                Wl + (long)(o0 + nrow) * 384 + ks * 32 + quad * 8;
            bf16x8 a0 = *(const bf16x8*)(wr);
            bf16x8 a1 = *(const bf16x8*)(wr + 16 * 384);
            #pragma unroll
            for (int nt = 0; nt < 6; ++nt) {
                bf16x8 bf = *(const bf16x8*)&xhi[(roff + nt * 16) * LROW + c0];
                acc[0][nt] = __builtin_amdgcn_mfma_f32_16x16x32_bf16(
                    a0, bf, acc[0][nt], 0, 0, 0);
                acc[1][nt] = __builtin_amdgcn_mfma_f32_16x16x32_bf16(
                    a1, bf, acc[1][nt], 0, 0, 0);
            }
        }

        // fold bias into acc (residual already carried in acc)
        #pragma unroll
        for (int mt = 0; mt < 2; ++mt) {
            int obase = o0 + mt * 16 + quad * 4;
            #pragma unroll
            for (int r = 0; r < 4; ++r) {
                float bv = bm[obase + r];
                #pragma unroll
                for (int nt = 0; nt < 6; ++nt)
                    acc[mt][nt][r] += bv;
            }
        }
        __syncthreads();   // all LDS reads of layer l done before any write

        if (l < 3) {
            // write back only the bf16 hi image for the next layer's B-operand
            #pragma unroll
            for (int mt = 0; mt < 2; ++mt) {
                int obase = o0 + mt * 16 + quad * 4;
                #pragma unroll
                for (int nt = 0; nt < 6; ++nt) {
                    int trow = GUARD + nt * 16 + nrow;
                    int tg = T0 - 16 + nt * 16 + nrow;
                    bool ok = ((unsigned)tg < (unsigned)TT);
                    u16x4 h;
                    #pragma unroll
                    for (int r = 0; r < 4; ++r) {
                        float v = ok ? acc[mt][nt][r] : 0.f;
                        h[r] = f2bf(v);
                    }
                    *(u16x4*)&xhi[trow * LROW + obase] = h;
                }
            }
            __syncthreads();
        } else {
            // final layer: sin activation, store only the valid 64-t core
            #pragma unroll
            for (int mt = 0; mt < 2; ++mt) {
                #pragma unroll
                for (int r = 0; r < 4; ++r) {
                    int o = o0 + mt * 16 + quad * 4 + r;
                    float av = alpha[o];
                    float rcp = 1.0f / (av + 1e-8f);
                    long rowoff = ((long)b * CHN + o) * TT + T0;
                    #pragma unroll
                    for (int nt = 1; nt < 5; ++nt) {
                        int t = (nt - 1) * 16 + nrow;
                        float xn = acc[mt][nt][r];
                        float s = __sinf(av * xn);
                        dst[rowoff + t] = xn + rcp * s * s;
                    }
                }
            }
        }
    }
}

extern "C" void kernel_launch(void* const* d_in, const int* in_sizes, int n_in,
                              void* d_out, int out_size, void* d_ws, size_t ws_size,
                              hipStream_t stream) {
    const float* x     = (const float*)d_in[0];
    const float* cond  = (const float*)d_in[1];
    const float* w0    = (const float*)d_in[2];
    const float* b0    = (const float*)d_in[3];
    const float* w1    = (const float*)d_in[4];
    const float* b1    = (const float*)d_in[5];
    const float* w2    = (const float*)d_in[6];
    const float* b2    = (const float*)d_in[7];
    const float* alpha = (const float*)d_in[8];
    float* out = (float*)d_out;

    char* ws = (char*)d_ws;
    unsigned short* W = (unsigned short*)ws;               // 3,145,728 B
    float* bmean = (float*)(ws + 3145728);                 // 16,384 B
    float* hbar  = (float*)(ws + 3162112);                 // 2,048 B
    float* h0    = (float*)(ws + 3164160);                 // 65,536 B

    k_cond0<<<64, 256, 0, stream>>>(cond, w0, b0, h0);
    k_cond1<<<64, 256, 0, stream>>>(h0, w1, b1, hbar);
    k_weights<<<772, 256, 0, stream>>>(w2, b2, hbar, W, bmean);
    k_fused<<<2048, 256, 0, stream>>>(x, out, W, bmean, alpha);
}